// Round 11
// baseline (324.881 us; speedup 1.0000x reference)
//
#include <hip/hip_runtime.h>

#define B_ 8
#define L_ 2048
#define CIN_ 256
#define COUT_ 256
#define HEADS_ 4
#define HD_ 64
#define NEG_SLOPE_ 0.2f
#define LOG2E_ 1.4426950408889634f

#define TI 32   // proj i-rows per block
#define TJ 64   // attn j-cols per tile
#define NJT (L_ / TJ)

typedef __attribute__((ext_vector_type(4))) float f32x4;
typedef __attribute__((ext_vector_type(8))) __bf16 bf16x8;
typedef __attribute__((ext_vector_type(4))) __bf16 bf16x4;

// MFMA 16x16x32 bf16 layouts (m89/m120-verified):
//  A[m][k]: m = lane&15, k = (lane>>4)*8 + e
//  B[k][n]: n = lane&15, k = (lane>>4)*8 + e
//  D[m][n]: n = lane&15, m = (lane>>4)*4 + reg
//
// hF ("B-frag-linear" h): for (b,h,jt,kt,nt) a 512-elem block, element
// (q*16+col)*8+e = h[channel h*64+nt*16+col][j = jt*64+kt*32+q*8+e].
//
// Rank-1 factorization (R10): exp(leaky(a_i+d_j)) = max(E_i*F_j, E'_i*F'_j),
// E=2^(k a), E'=2^(0.2k a), F=2^(k d), F'=2^(0.2k d), k=log2(e) — exact by
// monotonicity of exp2. No transcendentals in the attn hot loop.
// abitsT transposed masks: abitsT[b][jw][row] (jw = j/64).

// ---------------------------------------------------------------------------
// Kernel 1 (R11: pack FUSED in): packs this block's slice of adj -> abitsT,
// then h = x@W^T via MFMA -> hF + (E,E')/(F,F') factor pairs.
// grid 512 x 256 thr; block = 32 seq rows, wave w = head w.
// pack slice: 256 ballot-chunks/block (64/wave); its HBM stream overlaps the
// co-resident block's GEMM work (2 blocks/CU).
// ---------------------------------------------------------------------------
__global__ __launch_bounds__(256, 2)
void proj_kernel(const float* __restrict__ x, const float* __restrict__ W,
                 const float* __restrict__ att_src, const float* __restrict__ att_dst,
                 const int* __restrict__ adj, unsigned long long* __restrict__ abitsT,
                 __bf16* __restrict__ hF, float2* __restrict__ aE,
                 float2* __restrict__ aF) {
  __shared__ __align__(16) __bf16 Wl[COUT_][80];
  __shared__ __align__(16) __bf16 Al[2][2][512];

  const int tid = threadIdx.x;
  const int r0 = blockIdx.x * TI;
  const int b  = r0 >> 11;
  const int l0 = r0 & (L_ - 1);

  const int w = tid >> 6, lane = tid & 63, col = lane & 15, q = lane >> 4;
  const int si = tid >> 3, soct = tid & 7;
  const int wn = tid >> 2, wkq = tid & 3;

  // ---- fused pack: 64 chunks per wave (chunk = 256 adj ints -> 4 u64) ----
  {
    const size_t wid0 = (size_t)blockIdx.x * 256 + (size_t)w * 64;
    for (int c = 0; c < 64; ++c) {
      const size_t wid = wid0 + c;
      const int* p = adj + wid * 256 + lane;
      unsigned long long b0 = __ballot(p[0]   != 0);
      unsigned long long b1 = __ballot(p[64]  != 0);
      unsigned long long b2 = __ballot(p[128] != 0);
      unsigned long long b3 = __ballot(p[192] != 0);
      if (lane == 0) {
        const size_t row = wid >> 3;          // b*2048 + i
        const int jw0 = (int)(wid & 7) * 4;
        const size_t bb = row >> 11, l = row & 2047;
        unsigned long long* dst = abitsT + (bb << 16) + l;
        dst[(size_t)(jw0 + 0) << 11] = b0;
        dst[(size_t)(jw0 + 1) << 11] = b1;
        dst[(size_t)(jw0 + 2) << 11] = b2;
        dst[(size_t)(jw0 + 3) << 11] = b3;
      }
    }
  }

  f32x4 acc[2][4];
#pragma unroll
  for (int mt = 0; mt < 2; ++mt)
#pragma unroll
    for (int nt = 0; nt < 4; ++nt) acc[mt][nt] = (f32x4)0.f;

  for (int kc = 0; kc < CIN_ / 64; ++kc) {
    __syncthreads();
#pragma unroll
    for (int rg = 0; rg < 4; ++rg) {
      const int row = rg * 64 + wn;
      const float4* ws = (const float4*)(W + (size_t)row * CIN_ + kc * 64 + wkq * 16);
#pragma unroll
      for (int u = 0; u < 4; ++u) {
        float4 f = ws[u];
        bf16x4 v;
        v[0] = (__bf16)f.x; v[1] = (__bf16)f.y; v[2] = (__bf16)f.z; v[3] = (__bf16)f.w;
        *(bf16x4*)&Wl[row][wkq * 16 + u * 4] = v;
      }
    }
    {
      const float4* xs = (const float4*)(x + (size_t)(r0 + si) * CIN_ + kc * 64 + soct * 8);
      float4 f0 = xs[0], f1 = xs[1];
      bf16x8 v;
      v[0] = (__bf16)f0.x; v[1] = (__bf16)f0.y; v[2] = (__bf16)f0.z; v[3] = (__bf16)f0.w;
      v[4] = (__bf16)f1.x; v[5] = (__bf16)f1.y; v[6] = (__bf16)f1.z; v[7] = (__bf16)f1.w;
      *(bf16x8*)&Al[si >> 4][soct >> 2][(((soct & 3) << 4) + (si & 15)) << 3] = v;
    }
    __syncthreads();

    bf16x8 af[2][2], bfr[2][4];
#pragma unroll
    for (int mt = 0; mt < 2; ++mt)
#pragma unroll
      for (int kt = 0; kt < 2; ++kt)
        af[mt][kt] = *(const bf16x8*)&Al[mt][kt][lane << 3];
#pragma unroll
    for (int kt = 0; kt < 2; ++kt)
#pragma unroll
      for (int nt = 0; nt < 4; ++nt)
        bfr[kt][nt] = *(const bf16x8*)&Wl[w * 64 + nt * 16 + col][kt * 32 + q * 8];
#pragma unroll
    for (int kt = 0; kt < 2; ++kt)
#pragma unroll
      for (int mt = 0; mt < 2; ++mt)
#pragma unroll
        for (int nt = 0; nt < 4; ++nt)
          acc[mt][nt] = __builtin_amdgcn_mfma_f32_16x16x32_bf16(
              af[mt][kt], bfr[kt][nt], acc[mt][nt], 0, 0, 0);
  }

  // ---- fused score factors ----
  float asv[4], adv[4];
#pragma unroll
  for (int nt = 0; nt < 4; ++nt) {
    asv[nt] = att_src[w * 64 + nt * 16 + col];
    adv[nt] = att_dst[w * 64 + nt * 16 + col];
  }
#pragma unroll
  for (int mt = 0; mt < 2; ++mt)
#pragma unroll
    for (int reg = 0; reg < 4; ++reg) {
      float s = 0.f, d = 0.f;
#pragma unroll
      for (int nt = 0; nt < 4; ++nt) {
        s = fmaf(acc[mt][nt][reg], asv[nt], s);
        d = fmaf(acc[mt][nt][reg], adv[nt], d);
      }
      s += __shfl_xor(s, 1, 64); d += __shfl_xor(d, 1, 64);
      s += __shfl_xor(s, 2, 64); d += __shfl_xor(d, 2, 64);
      s += __shfl_xor(s, 4, 64); d += __shfl_xor(d, 4, 64);
      s += __shfl_xor(s, 8, 64); d += __shfl_xor(d, 8, 64);
      if (col == 0) {
        int il = mt * 16 + q * 4 + reg;
        const size_t idx = ((size_t)(b * HEADS_ + w) << 11) + l0 + il;
        float2 ev, fv;
        ev.x = __builtin_exp2f(s * LOG2E_);
        ev.y = __builtin_exp2f(s * (LOG2E_ * NEG_SLOPE_));
        fv.x = __builtin_exp2f(d * LOG2E_);
        fv.y = __builtin_exp2f(d * (LOG2E_ * NEG_SLOPE_));
        aE[idx] = ev;
        aF[idx] = fv;
      }
    }

  // ---- hF write: D-frag -> B-frag-linear ----
  {
    const int jt_p = l0 >> 6;
    const int kt_p = (l0 >> 5) & 1;
    const int qhi = q >> 1, qlo = q & 1;
#pragma unroll
    for (int mt = 0; mt < 2; ++mt) {
      const int qp = mt * 2 + qhi;
#pragma unroll
      for (int nt = 0; nt < 4; ++nt) {
        bf16x4 v;
        v[0] = (__bf16)acc[mt][nt][0];
        v[1] = (__bf16)acc[mt][nt][1];
        v[2] = (__bf16)acc[mt][nt][2];
        v[3] = (__bf16)acc[mt][nt][3];
        const size_t off =
            ((((size_t)(b * HEADS_ + w) * 32 + jt_p) * 2 + kt_p) * 4 + nt) * 512 +
            (qp * 16 + col) * 8 + qlo * 4;
        *(bf16x4*)(hF + off) = v;
      }
    }
  }
}

// ---------------------------------------------------------------------------
// Kernel 2 (R11): split-j attention. 512 thr = 8 waves = 4 heads x 2 j-halves;
// each wave runs 16 j-tiles (transcendental-free P = masked max(E*F,E'*F')),
// partial (O,l) combined via LDS + one barrier. grid 512 -> 2 blocks/CU ->
// 4 waves/SIMD (2x R10 occupancy, same total L2 traffic).
// ---------------------------------------------------------------------------
__global__ __launch_bounds__(512, 4)
void attn_kernel(const __bf16* __restrict__ hF, const float2* __restrict__ aE,
                 const float2* __restrict__ aF,
                 const unsigned long long* __restrict__ abitsT,
                 float* __restrict__ out) {
  __shared__ __align__(16) float comb[HEADS_][64][40];   // 40 KB combine buf

  const int tid = threadIdx.x;
  const int b  = blockIdx.x & 7;           // XCD swizzle
  const int i0 = (blockIdx.x >> 3) * 32;

  const int w = tid >> 6, lane = tid & 63, col = lane & 15, q = lane >> 4;
  const int hh = w & 3;                    // head
  const int jh = w >> 2;                   // j-half
  const int jt0 = jh * (NJT / 2), jt1 = jt0 + NJT / 2;

  const size_t hl = (size_t)(b * HEADS_ + hh);
  const float2 EE[2] = {aE[(hl << 11) + i0 + col],
                        aE[(hl << 11) + i0 + 16 + col]};
  const float* afb = (const float*)(aF + (hl << 11)) + q * 16;
  const __bf16* hb = hF + hl * 131072 + lane * 8;
  const unsigned long long* mb = abitsT + ((size_t)b << 16) + i0 + col;

  bf16x8 bones;
#pragma unroll
  for (int e = 0; e < 8; ++e) bones[e] = (__bf16)1.0f;

  f32x4 acc[2][4], accl[2];
#pragma unroll
  for (int mt = 0; mt < 2; ++mt) {
    accl[mt] = (f32x4)0.f;
#pragma unroll
    for (int nt = 0; nt < 4; ++nt) acc[mt][nt] = (f32x4)0.f;
  }

  unsigned long long cm0 = mb[(size_t)jt0 << 11];
  unsigned long long cm1 = mb[((size_t)jt0 << 11) + 16];

  for (int jt = jt0; jt < jt1; ++jt) {
    // loads for THIS tile (L2; latency hides behind VALU + 4-wave TLP)
    bf16x8 cb[2][4];
#pragma unroll
    for (int kt = 0; kt < 2; ++kt)
#pragma unroll
      for (int nt = 0; nt < 4; ++nt)
        cb[kt][nt] = *(const bf16x8*)(hb + jt * 4096 + (kt * 4 + nt) * 512);
    float cf[2][16];
#pragma unroll
    for (int kt = 0; kt < 2; ++kt)
#pragma unroll
      for (int u = 0; u < 4; ++u)
        *(float4*)&cf[kt][u * 4] =
            *(const float4*)(afb + jt * 128 + kt * 64 + u * 4);

    const int jn = (jt < jt1 - 1) ? jt + 1 : jt;
    const unsigned long long nm0 = mb[(size_t)jn << 11];
    const unsigned long long nm1 = mb[((size_t)jn << 11) + 16];

    // phase 1: P = masked max(E*F, E'*F') in A-frag order
    bf16x8 av[2][2];
#pragma unroll
    for (int mt = 0; mt < 2; ++mt) {
      const unsigned long long bw = mt ? cm1 : cm0;
      const float Ex = EE[mt].x, Ey = EE[mt].y;
#pragma unroll
      for (int kt = 0; kt < 2; ++kt) {
        const unsigned int tsh = ((unsigned int)(bw >> (kt * 32))) >> (q * 8);
#pragma unroll
        for (int e = 0; e < 8; ++e) {
          const float m1 = Ex * cf[kt][2 * e];
          const float m2 = Ey * cf[kt][2 * e + 1];
          const float pm = fmaxf(m1, m2);
          const float p = (tsh & (1u << e)) ? pm : 0.f;
          av[mt][kt][e] = (__bf16)p;
        }
      }
    }

    // phase 2: 16 MFMA for O, 4 for l
#pragma unroll
    for (int kt = 0; kt < 2; ++kt)
#pragma unroll
      for (int mt = 0; mt < 2; ++mt) {
#pragma unroll
        for (int nt = 0; nt < 4; ++nt)
          acc[mt][nt] = __builtin_amdgcn_mfma_f32_16x16x32_bf16(
              av[mt][kt], cb[kt][nt], acc[mt][nt], 0, 0, 0);
        accl[mt] = __builtin_amdgcn_mfma_f32_16x16x32_bf16(
            av[mt][kt], bones, accl[mt], 0, 0, 0);
      }

    cm0 = nm0; cm1 = nm1;
  }

  // ---- combine j-halves via LDS ----
  if (jh == 1) {
#pragma unroll
    for (int mt = 0; mt < 2; ++mt)
#pragma unroll
      for (int nt = 0; nt < 4; ++nt)
        *(f32x4*)&comb[hh][lane][mt * 16 + nt * 4] = acc[mt][nt];
    *(f32x4*)&comb[hh][lane][32] = accl[0];
    *(f32x4*)&comb[hh][lane][36] = accl[1];
  }
  __syncthreads();
  if (jh == 0) {
#pragma unroll
    for (int mt = 0; mt < 2; ++mt) {
      const f32x4 lo = accl[mt] + *(const f32x4*)&comb[hh][lane][32 + mt * 4];
#pragma unroll
      for (int reg = 0; reg < 4; ++reg) {
        const int m = q * 4 + reg;
        const float linv = 1.0f / lo[reg];
        const size_t orow =
            ((size_t)(b * L_ + i0 + mt * 16 + m)) * COUT_ + hh * 64;
#pragma unroll
        for (int nt = 0; nt < 4; ++nt) {
          const float v =
              acc[mt][nt][reg] + comb[hh][lane][mt * 16 + nt * 4 + reg];
          out[orow + nt * 16 + col] = v * linv;
        }
      }
    }
  }
}

// ---------------------------------------------------------------------------
extern "C" void kernel_launch(void* const* d_in, const int* in_sizes, int n_in,
                              void* d_out, int out_size, void* d_ws, size_t ws_size,
                              hipStream_t stream) {
  const float* x       = (const float*)d_in[0];
  const int*   adj     = (const int*)d_in[1];
  const float* W       = (const float*)d_in[2];
  const float* att_src = (const float*)d_in[3];
  const float* att_dst = (const float*)d_in[4];
  float* out = (float*)d_out;

  char* ws = (char*)d_ws;
  __bf16* hF = (__bf16*)ws;                                   // 8 MB frag-linear
  float2* aE = (float2*)(ws + (8u << 20));                    // 512 KB (E,E')
  float2* aF = (float2*)(ws + (9u << 20));                    // 512 KB (F,F')
  unsigned long long* abitsT =
      (unsigned long long*)(ws + (10u << 20));                // 4 MB transposed

  proj_kernel<<<(B_ * L_) / TI, 256, 0, stream>>>(x, W, att_src, att_dst,
                                                  adj, abitsT, hF, aE, aF);
  attn_kernel<<<B_ * (L_ / 32), 512, 0, stream>>>(hF, aE, aF, abitsT, out);
}

// Round 12
// 261.078 us; speedup vs baseline: 1.2444x; 1.2444x over previous
//
#include <hip/hip_runtime.h>

#define B_ 8
#define L_ 2048
#define CIN_ 256
#define COUT_ 256
#define HEADS_ 4
#define HD_ 64
#define NEG_SLOPE_ 0.2f
#define LOG2E_ 1.4426950408889634f

#define TI 32   // proj i-rows per block
#define TJ 64   // attn j-cols per tile
#define NJT (L_ / TJ)

typedef __attribute__((ext_vector_type(4))) float f32x4;
typedef __attribute__((ext_vector_type(8))) __bf16 bf16x8;
typedef __attribute__((ext_vector_type(4))) __bf16 bf16x4;

// MFMA 16x16x32 bf16 layouts (m89/m120-verified):
//  A[m][k]: m = lane&15, k = (lane>>4)*8 + e
//  B[k][n]: n = lane&15, k = (lane>>4)*8 + e
//  D[m][n]: n = lane&15, m = (lane>>4)*4 + reg
//
// hF ("B-frag-linear" h): for (b,h,jt,kt,nt) a 512-elem block, element
// (q*16+col)*8+e = h[channel h*64+nt*16+col][j = jt*64+kt*32+q*8+e].
// Rank-1 factorization: exp(leaky(a_i+d_j)) = max(E_i*F_j, E'_i*F'_j) — exact.
// abitsT transposed masks: abitsT[b][jw][row] (jw = j/64).

// ---------------------------------------------------------------------------
// Kernel 0: pack adj int32 -> 1 bit, TRANSPOSED layout abitsT[b][jw][row].
// ---------------------------------------------------------------------------
__global__ __launch_bounds__(256, 4)
void pack_kernel(const int* __restrict__ adj, unsigned long long* __restrict__ abitsT) {
  const size_t wid = ((size_t)blockIdx.x * 256 + threadIdx.x) >> 6;  // 256-int chunk
  const int lane = threadIdx.x & 63;
  const int* p = adj + wid * 256 + lane;
  unsigned long long b0 = __ballot(p[0]   != 0);
  unsigned long long b1 = __ballot(p[64]  != 0);
  unsigned long long b2 = __ballot(p[128] != 0);
  unsigned long long b3 = __ballot(p[192] != 0);
  if (lane == 0) {
    const size_t row = wid >> 3;           // global row = b*2048 + i
    const int jw0 = (int)(wid & 7) * 4;    // first j-word of this chunk
    const size_t bb = row >> 11, l = row & 2047;
    unsigned long long* dst = abitsT + (bb << 16) + l;   // b*32*2048 + i
    dst[(size_t)(jw0 + 0) << 11] = b0;
    dst[(size_t)(jw0 + 1) << 11] = b1;
    dst[(size_t)(jw0 + 2) << 11] = b2;
    dst[(size_t)(jw0 + 3) << 11] = b3;
  }
}

// ---------------------------------------------------------------------------
// Kernel 1: h = x@W^T via MFMA -> hF (B-frag-linear bf16) + (E,E')/(F,F')
// factor pairs. grid 512 x 256 thr; block = 32 seq rows, wave w = head w.
// ---------------------------------------------------------------------------
__global__ __launch_bounds__(256, 2)
void proj_kernel(const float* __restrict__ x, const float* __restrict__ W,
                 const float* __restrict__ att_src, const float* __restrict__ att_dst,
                 __bf16* __restrict__ hF, float2* __restrict__ aE,
                 float2* __restrict__ aF) {
  __shared__ __align__(16) __bf16 Wl[COUT_][80];
  __shared__ __align__(16) __bf16 Al[2][2][512];

  const int tid = threadIdx.x;
  const int r0 = blockIdx.x * TI;
  const int b  = r0 >> 11;
  const int l0 = r0 & (L_ - 1);

  const int w = tid >> 6, lane = tid & 63, col = lane & 15, q = lane >> 4;
  const int si = tid >> 3, soct = tid & 7;
  const int wn = tid >> 2, wkq = tid & 3;

  f32x4 acc[2][4];
#pragma unroll
  for (int mt = 0; mt < 2; ++mt)
#pragma unroll
    for (int nt = 0; nt < 4; ++nt) acc[mt][nt] = (f32x4)0.f;

  for (int kc = 0; kc < CIN_ / 64; ++kc) {
    __syncthreads();
#pragma unroll
    for (int rg = 0; rg < 4; ++rg) {
      const int row = rg * 64 + wn;
      const float4* ws = (const float4*)(W + (size_t)row * CIN_ + kc * 64 + wkq * 16);
#pragma unroll
      for (int u = 0; u < 4; ++u) {
        float4 f = ws[u];
        bf16x4 v;
        v[0] = (__bf16)f.x; v[1] = (__bf16)f.y; v[2] = (__bf16)f.z; v[3] = (__bf16)f.w;
        *(bf16x4*)&Wl[row][wkq * 16 + u * 4] = v;
      }
    }
    {
      const float4* xs = (const float4*)(x + (size_t)(r0 + si) * CIN_ + kc * 64 + soct * 8);
      float4 f0 = xs[0], f1 = xs[1];
      bf16x8 v;
      v[0] = (__bf16)f0.x; v[1] = (__bf16)f0.y; v[2] = (__bf16)f0.z; v[3] = (__bf16)f0.w;
      v[4] = (__bf16)f1.x; v[5] = (__bf16)f1.y; v[6] = (__bf16)f1.z; v[7] = (__bf16)f1.w;
      *(bf16x8*)&Al[si >> 4][soct >> 2][(((soct & 3) << 4) + (si & 15)) << 3] = v;
    }
    __syncthreads();

    bf16x8 af[2][2], bfr[2][4];
#pragma unroll
    for (int mt = 0; mt < 2; ++mt)
#pragma unroll
      for (int kt = 0; kt < 2; ++kt)
        af[mt][kt] = *(const bf16x8*)&Al[mt][kt][lane << 3];
#pragma unroll
    for (int kt = 0; kt < 2; ++kt)
#pragma unroll
      for (int nt = 0; nt < 4; ++nt)
        bfr[kt][nt] = *(const bf16x8*)&Wl[w * 64 + nt * 16 + col][kt * 32 + q * 8];
#pragma unroll
    for (int kt = 0; kt < 2; ++kt)
#pragma unroll
      for (int mt = 0; mt < 2; ++mt)
#pragma unroll
        for (int nt = 0; nt < 4; ++nt)
          acc[mt][nt] = __builtin_amdgcn_mfma_f32_16x16x32_bf16(
              af[mt][kt], bfr[kt][nt], acc[mt][nt], 0, 0, 0);
  }

  // ---- fused score factors ----
  float asv[4], adv[4];
#pragma unroll
  for (int nt = 0; nt < 4; ++nt) {
    asv[nt] = att_src[w * 64 + nt * 16 + col];
    adv[nt] = att_dst[w * 64 + nt * 16 + col];
  }
#pragma unroll
  for (int mt = 0; mt < 2; ++mt)
#pragma unroll
    for (int reg = 0; reg < 4; ++reg) {
      float s = 0.f, d = 0.f;
#pragma unroll
      for (int nt = 0; nt < 4; ++nt) {
        s = fmaf(acc[mt][nt][reg], asv[nt], s);
        d = fmaf(acc[mt][nt][reg], adv[nt], d);
      }
      s += __shfl_xor(s, 1, 64); d += __shfl_xor(d, 1, 64);
      s += __shfl_xor(s, 2, 64); d += __shfl_xor(d, 2, 64);
      s += __shfl_xor(s, 4, 64); d += __shfl_xor(d, 4, 64);
      s += __shfl_xor(s, 8, 64); d += __shfl_xor(d, 8, 64);
      if (col == 0) {
        int il = mt * 16 + q * 4 + reg;
        const size_t idx = ((size_t)(b * HEADS_ + w) << 11) + l0 + il;
        float2 ev, fv;
        ev.x = __builtin_exp2f(s * LOG2E_);
        ev.y = __builtin_exp2f(s * (LOG2E_ * NEG_SLOPE_));
        fv.x = __builtin_exp2f(d * LOG2E_);
        fv.y = __builtin_exp2f(d * (LOG2E_ * NEG_SLOPE_));
        aE[idx] = ev;
        aF[idx] = fv;
      }
    }

  // ---- hF write: D-frag -> B-frag-linear ----
  {
    const int jt_p = l0 >> 6;
    const int kt_p = (l0 >> 5) & 1;
    const int qhi = q >> 1, qlo = q & 1;
#pragma unroll
    for (int mt = 0; mt < 2; ++mt) {
      const int qp = mt * 2 + qhi;
#pragma unroll
      for (int nt = 0; nt < 4; ++nt) {
        bf16x4 v;
        v[0] = (__bf16)acc[mt][nt][0];
        v[1] = (__bf16)acc[mt][nt][1];
        v[2] = (__bf16)acc[mt][nt][2];
        v[3] = (__bf16)acc[mt][nt][3];
        const size_t off =
            ((((size_t)(b * HEADS_ + w) * 32 + jt_p) * 2 + kt_p) * 4 + nt) * 512 +
            (qp * 16 + col) * 8 + qlo * 4;
        *(bf16x4*)(hF + off) = v;
      }
    }
  }
}

// ---------------------------------------------------------------------------
// Kernel 2 (R12): split-j attention, NO launch-bounds VGPR cap (R11's
// (512,4) forced a 64-VGPR budget -> 134 MB scratch spill). Per-kt inner
// structure keeps peak liveness ~100 VGPRs. 512 thr = 8 waves = 4 heads x
// 2 j-halves; partial (O,l) combined via LDS + one barrier.
// ---------------------------------------------------------------------------
__global__ __launch_bounds__(512)
void attn_kernel(const __bf16* __restrict__ hF, const float2* __restrict__ aE,
                 const float2* __restrict__ aF,
                 const unsigned long long* __restrict__ abitsT,
                 float* __restrict__ out) {
  __shared__ __align__(16) float comb[HEADS_][64][40];   // 40 KB combine buf

  const int tid = threadIdx.x;
  const int b  = blockIdx.x & 7;           // XCD swizzle
  const int i0 = (blockIdx.x >> 3) * 32;

  const int w = tid >> 6, lane = tid & 63, col = lane & 15, q = lane >> 4;
  const int hh = w & 3;                    // head
  const int jh = w >> 2;                   // j-half
  const int jt0 = jh * (NJT / 2), jt1 = jt0 + NJT / 2;

  const size_t hl = (size_t)(b * HEADS_ + hh);
  const float2 EE[2] = {aE[(hl << 11) + i0 + col],
                        aE[(hl << 11) + i0 + 16 + col]};
  const float* afb = (const float*)(aF + (hl << 11)) + q * 16;
  const __bf16* hb = hF + hl * 131072 + lane * 8;
  const unsigned long long* mb = abitsT + ((size_t)b << 16) + i0 + col;

  bf16x8 bones;
#pragma unroll
  for (int e = 0; e < 8; ++e) bones[e] = (__bf16)1.0f;

  f32x4 acc[2][4], accl[2];
#pragma unroll
  for (int mt = 0; mt < 2; ++mt) {
    accl[mt] = (f32x4)0.f;
#pragma unroll
    for (int nt = 0; nt < 4; ++nt) acc[mt][nt] = (f32x4)0.f;
  }

  unsigned long long cm0 = mb[(size_t)jt0 << 11];
  unsigned long long cm1 = mb[((size_t)jt0 << 11) + 16];

  for (int jt = jt0; jt < jt1; ++jt) {
    const int jn = (jt < jt1 - 1) ? jt + 1 : jt;
    const unsigned long long nm0 = mb[(size_t)jn << 11];
    const unsigned long long nm1 = mb[((size_t)jn << 11) + 16];

    // per-kt: load 4 cb frags + 4 cf float4s, build av for both mt, 10 MFMAs.
#pragma unroll
    for (int kt = 0; kt < 2; ++kt) {
      bf16x8 cb0 = *(const bf16x8*)(hb + jt * 4096 + (kt * 4 + 0) * 512);
      bf16x8 cb1 = *(const bf16x8*)(hb + jt * 4096 + (kt * 4 + 1) * 512);
      bf16x8 cb2 = *(const bf16x8*)(hb + jt * 4096 + (kt * 4 + 2) * 512);
      bf16x8 cb3 = *(const bf16x8*)(hb + jt * 4096 + (kt * 4 + 3) * 512);
      float cf[16];
#pragma unroll
      for (int u = 0; u < 4; ++u)
        *(float4*)&cf[u * 4] =
            *(const float4*)(afb + jt * 128 + kt * 64 + u * 4);

      bf16x8 av[2];
#pragma unroll
      for (int mt = 0; mt < 2; ++mt) {
        const unsigned long long bw = mt ? cm1 : cm0;
        const unsigned int tsh = ((unsigned int)(bw >> (kt * 32))) >> (q * 8);
        const float Ex = EE[mt].x, Ey = EE[mt].y;
#pragma unroll
        for (int e = 0; e < 8; ++e) {
          const float m1 = Ex * cf[2 * e];
          const float m2 = Ey * cf[2 * e + 1];
          const float pm = fmaxf(m1, m2);
          const float p = (tsh & (1u << e)) ? pm : 0.f;
          av[mt][e] = (__bf16)p;
        }
      }
#pragma unroll
      for (int mt = 0; mt < 2; ++mt) {
        acc[mt][0] = __builtin_amdgcn_mfma_f32_16x16x32_bf16(av[mt], cb0, acc[mt][0], 0, 0, 0);
        acc[mt][1] = __builtin_amdgcn_mfma_f32_16x16x32_bf16(av[mt], cb1, acc[mt][1], 0, 0, 0);
        acc[mt][2] = __builtin_amdgcn_mfma_f32_16x16x32_bf16(av[mt], cb2, acc[mt][2], 0, 0, 0);
        acc[mt][3] = __builtin_amdgcn_mfma_f32_16x16x32_bf16(av[mt], cb3, acc[mt][3], 0, 0, 0);
        accl[mt] = __builtin_amdgcn_mfma_f32_16x16x32_bf16(av[mt], bones, accl[mt], 0, 0, 0);
      }
    }

    cm0 = nm0; cm1 = nm1;
  }

  // ---- combine j-halves via LDS ----
  if (jh == 1) {
#pragma unroll
    for (int mt = 0; mt < 2; ++mt)
#pragma unroll
      for (int nt = 0; nt < 4; ++nt)
        *(f32x4*)&comb[hh][lane][mt * 16 + nt * 4] = acc[mt][nt];
    *(f32x4*)&comb[hh][lane][32] = accl[0];
    *(f32x4*)&comb[hh][lane][36] = accl[1];
  }
  __syncthreads();
  if (jh == 0) {
#pragma unroll
    for (int mt = 0; mt < 2; ++mt) {
      const f32x4 lo = accl[mt] + *(const f32x4*)&comb[hh][lane][32 + mt * 4];
#pragma unroll
      for (int reg = 0; reg < 4; ++reg) {
        const int m = q * 4 + reg;
        const float linv = 1.0f / lo[reg];
        const size_t orow =
            ((size_t)(b * L_ + i0 + mt * 16 + m)) * COUT_ + hh * 64;
#pragma unroll
        for (int nt = 0; nt < 4; ++nt) {
          const float v =
              acc[mt][nt][reg] + comb[hh][lane][mt * 16 + nt * 4 + reg];
          out[orow + nt * 16 + col] = v * linv;
        }
      }
    }
  }
}

// ---------------------------------------------------------------------------
extern "C" void kernel_launch(void* const* d_in, const int* in_sizes, int n_in,
                              void* d_out, int out_size, void* d_ws, size_t ws_size,
                              hipStream_t stream) {
  const float* x       = (const float*)d_in[0];
  const int*   adj     = (const int*)d_in[1];
  const float* W       = (const float*)d_in[2];
  const float* att_src = (const float*)d_in[3];
  const float* att_dst = (const float*)d_in[4];
  float* out = (float*)d_out;

  char* ws = (char*)d_ws;
  __bf16* hF = (__bf16*)ws;                                   // 8 MB frag-linear
  float2* aE = (float2*)(ws + (8u << 20));                    // 512 KB (E,E')
  float2* aF = (float2*)(ws + (9u << 20));                    // 512 KB (F,F')
  unsigned long long* abitsT =
      (unsigned long long*)(ws + (10u << 20));                // 4 MB transposed

  pack_kernel<<<(B_ * L_ * (L_ / 256)) / 4, 256, 0, stream>>>(adj, abitsT);
  proj_kernel<<<(B_ * L_) / TI, 256, 0, stream>>>(x, W, att_src, att_dst, hF, aE, aF);
  attn_kernel<<<B_ * (L_ / 32), 512, 0, stream>>>(hF, aE, aF, abitsT, out);
}